// Round 16
// baseline (239.069 us; speedup 1.0000x reference)
//
#include <hip/hip_runtime.h>

namespace {
constexpr int NB = 1024, NC = 128, NL = 16, NE = 10, NOUT = 4 * NC;
constexpr int NTHREADS = 256;
constexpr int NSPLIT = 2;
constexpr int P3_0 = 23, P2_0 = 4, P3_1 = 37, P2_1 = 6;
// fallback (fp32, 4-pad) constants
constexpr int TRI_P = 1040, DUO_P = 160, CSTRIDE = 1224;
// main path: tri 8-padded bf16
constexpr int TRI_P8 = 1376;           // bf16 values (runs padded to x8)
constexpr int TRI_W = TRI_P8 / 2;      // 688 u32 words
constexpr int S2_OFF = TRI_W;          // float offset of s2 (fp32, 4-pad, 160)
constexpr int S1_OFF = S2_OFF + DUO_P; // 848
constexpr int CSTRIDE_U = 872;         // words per channel (mult of 4)
constexpr int U3ROWS = P3_0 + 3 * P3_1;          // 134
constexpr int U2ROWS = P2_0 + 3 * P2_1;          // 22
constexpr int SYM3_FLOATS = U3ROWS * TRI_P8;     // 184384
constexpr int SYM2_FLOATS = U2ROWS * DUO_P;      // 3520
constexpr int SYM_TOTAL = SYM3_FLOATS + SYM2_FLOATS;  // 187904
// ws layout (float offsets)
constexpr int OFF_CNT = 0;
constexpr int OFF_NID = 16;                          // -> 10256
constexpr int OFF_SYM3A = 10272;
constexpr int OFF_SYM2A = OFF_SYM3A + SYM3_FLOATS;   // 194656
constexpr int WS_REQ = OFF_SYM2A + SYM2_FLOATS;      // 198176 floats (~793 KB)
}

__device__ __forceinline__ unsigned bfpack(float a, float b) {
    unsigned ua = __float_as_uint(a); ua = (ua + 0x7FFFu + ((ua >> 16) & 1u)) >> 16;
    unsigned ub = __float_as_uint(b); ub = (ub + 0x7FFFu + ((ub >> 16) & 1u)) >> 16;
    return ua | (ub << 16);
}
__device__ __forceinline__ void bfun8(uint4 p, float* __restrict__ f) {
    f[0] = __uint_as_float(p.x << 16); f[1] = __uint_as_float(p.x & 0xffff0000u);
    f[2] = __uint_as_float(p.y << 16); f[3] = __uint_as_float(p.y & 0xffff0000u);
    f[4] = __uint_as_float(p.z << 16); f[5] = __uint_as_float(p.z & 0xffff0000u);
    f[6] = __uint_as_float(p.w << 16); f[7] = __uint_as_float(p.w & 0xffff0000u);
}

// 8-padded tri mapping (main path)
__device__ __forceinline__ bool tri_from_padded8(int t, int& ri, int& rj, int& rm) {
    int pos = 0;
    for (int i = 0; i < 16; ++i)
        for (int j = i; j < 16; ++j) {
            const int L = 16 - j, PL = (L + 7) & ~7;
            if (t < pos + PL) { ri = i; rj = j; rm = j + (t - pos); return (t - pos) < L; }
            pos += PL;
        }
    return false;
}
// 4-padded mappings (fallback + duo)
__device__ __forceinline__ bool tri_from_padded(int t, int& ri, int& rj, int& rm) {
    int pos = 0;
    for (int i = 0; i < 16; ++i)
        for (int j = i; j < 16; ++j) {
            const int L = 16 - j, PL = (L + 3) & ~3;
            if (t < pos + PL) { ri = i; rj = j; rm = j + (t - pos); return (t - pos) < L; }
            pos += PL;
        }
    return false;
}
__device__ __forceinline__ bool duo_from_padded(int t, int& ri, int& rj) {
    int pos = 0;
    for (int i = 0; i < 16; ++i) {
        const int L = 16 - i, PL = (L + 3) & ~3;
        if (t < pos + PL) { ri = i; rj = i + (t - pos); return (t - pos) < L; }
        pos += PL;
    }
    return false;
}

// symmetrized U tables: tri 8-pad fp32 (k-major), duo 4-pad; pad positions = 0.
__device__ __forceinline__ void sym_body(int n,
    const float* __restrict__ U3_0e, const float* __restrict__ U3_1o,
    const float* __restrict__ U2_0e, const float* __restrict__ U2_1o,
    float* __restrict__ dst) {
    if (n < SYM3_FLOATS) {
        const int kk = n / TRI_P8, t = n - kk * TRI_P8;
        int pass, k, P; const float* U;
        if (kk < P3_0) { pass = 0; k = kk; P = P3_0; U = U3_0e; }
        else { const int r = kk - P3_0; pass = 1 + r / P3_1; k = r - (pass - 1) * P3_1;
               P = P3_1; U = U3_1o + (size_t)(pass - 1) * 4096 * P3_1; }
        int i, j, m; float s = 0.f;
        if (tri_from_padded8(t, i, j, m)) {
            auto u3 = [&](int a, int b, int c) {
                return U[(size_t)(((a << 4) + b) * 16 + c) * P + k]; };
            s = u3(i, j, m);
            if (i == j && j == m) {}
            else if (i == j) s += u3(i, m, i) + u3(m, i, i);
            else if (j == m) s += u3(j, i, j) + u3(j, j, i);
            else s += u3(i, m, j) + u3(j, i, m) + u3(j, m, i) + u3(m, i, j) + u3(m, j, i);
        }
        dst[n] = s;
    } else if (n < SYM_TOTAL) {
        const int r = n - SYM3_FLOATS;
        const int kk = r / DUO_P, t = r - kk * DUO_P;
        int pass, k, P; const float* U;
        if (kk < P2_0) { pass = 0; k = kk; P = P2_0; U = U2_0e; }
        else { const int q = kk - P2_0; pass = 1 + q / P2_1; k = q - (pass - 1) * P2_1;
               P = P2_1; U = U2_1o + (size_t)(pass - 1) * 256 * P2_1; }
        int i, j; float s = 0.f;
        if (duo_from_padded(t, i, j)) {
            auto u2 = [&](int a, int b) { return U[(size_t)((a << 4) + b) * P + k]; };
            s = u2(i, j) + (i < j ? u2(j, i) : 0.f);
        }
        dst[n] = s;
    }
}

// ===== Kernel A: blocks 0..NE-1 gather node lists; rest build sym tables =====
__global__ void prep_kernel(const float* __restrict__ y,
                            const float* __restrict__ U3_0e, const float* __restrict__ U3_1o,
                            const float* __restrict__ U2_0e, const float* __restrict__ U2_1o,
                            float* __restrict__ ws) {
    const int bid = blockIdx.x, tid = threadIdx.x;
    if (bid < NE) {
        __shared__ int s_scan[NTHREADS];
        const int e = bid;
        unsigned pat = 0;
#pragma unroll
        for (int q = 0; q < 4; ++q)
            if (y[(tid * 4 + q) * NE + e] > 0.5f) pat |= (1u << q);
        const int lc = __popc(pat);
        s_scan[tid] = lc;
        __syncthreads();
#pragma unroll
        for (int off = 1; off < NTHREADS; off <<= 1) {
            const int add = (tid >= off) ? s_scan[tid - off] : 0;
            __syncthreads();
            s_scan[tid] += add;
            __syncthreads();
        }
        int* cnt = (int*)ws + OFF_CNT;
        int* nid = (int*)ws + OFF_NID + e * NB;
        int pos = s_scan[tid] - lc;
#pragma unroll
        for (int q = 0; q < 4; ++q)
            if (pat & (1u << q)) nid[pos++] = tid * 4 + q;
        if (tid == 0) cnt[e] = s_scan[NTHREADS - 1];
    } else {
        const int n = (bid - NE) * NTHREADS + tid;
        sym_body(n, U3_0e, U3_1o, U2_0e, U2_1o, ws + OFF_SYM3A);
    }
}

// ===== build UW tile in LDS: tri packed bf16, s2 fp32; item = (t4, chpair) =====
// 8 accumulators + 1 float4 + 2 scalars live — fits the 64-VGPR envelope
// (R14's 16-acc version spilled 2.8 GB).
template <int P3c, int P2c>
__device__ __forceinline__ void build_lds(const float* __restrict__ sym3p,
                                          const float* __restrict__ sym2p,
                                          const float* __restrict__ s_w3,
                                          const float* __restrict__ s_w2,
                                          unsigned* __restrict__ s_ldsu, int tid)
{
    float* s_ldsf = reinterpret_cast<float*>(s_ldsu);
#pragma unroll 1
    for (int idx = tid; idx < (TRI_P8 / 4) * 2; idx += NTHREADS) {
        const int t4 = idx >> 1, cp = idx & 1;       // channels 2cp, 2cp+1
        float aLx = 0, aLy = 0, aLz = 0, aLw = 0;
        float aHx = 0, aHy = 0, aHz = 0, aHw = 0;
#pragma unroll 4
        for (int k = 0; k < P3c; ++k) {
            const float4 u = *reinterpret_cast<const float4*>(sym3p + (size_t)k * TRI_P8 + 4 * t4);
            const float wL = s_w3[4 * k + 2 * cp];
            const float wH = s_w3[4 * k + 2 * cp + 1];
            aLx = fmaf(u.x, wL, aLx); aLy = fmaf(u.y, wL, aLy);
            aLz = fmaf(u.z, wL, aLz); aLw = fmaf(u.w, wL, aLw);
            aHx = fmaf(u.x, wH, aHx); aHy = fmaf(u.y, wH, aHy);
            aHz = fmaf(u.z, wH, aHz); aHw = fmaf(u.w, wH, aHw);
        }
        *reinterpret_cast<uint2*>(s_ldsu + (2 * cp) * CSTRIDE_U + 2 * t4) =
            make_uint2(bfpack(aLx, aLy), bfpack(aLz, aLw));
        *reinterpret_cast<uint2*>(s_ldsu + (2 * cp + 1) * CSTRIDE_U + 2 * t4) =
            make_uint2(bfpack(aHx, aHy), bfpack(aHz, aHw));
    }
    if (tid < (DUO_P / 4) * 2) {
        const int t4 = tid >> 1, cp = tid & 1;
        float aLx = 0, aLy = 0, aLz = 0, aLw = 0;
        float aHx = 0, aHy = 0, aHz = 0, aHw = 0;
#pragma unroll
        for (int k = 0; k < P2c; ++k) {
            const float4 u = *reinterpret_cast<const float4*>(sym2p + (size_t)k * DUO_P + 4 * t4);
            const float wL = s_w2[4 * k + 2 * cp];
            const float wH = s_w2[4 * k + 2 * cp + 1];
            aLx = fmaf(u.x, wL, aLx); aLy = fmaf(u.y, wL, aLy);
            aLz = fmaf(u.z, wL, aLz); aLw = fmaf(u.w, wL, aLw);
            aHx = fmaf(u.x, wH, aHx); aHy = fmaf(u.y, wH, aHy);
            aHz = fmaf(u.z, wH, aHz); aHw = fmaf(u.w, wH, aHw);
        }
        *reinterpret_cast<float4*>(s_ldsf + (2 * cp) * CSTRIDE_U + S2_OFF + 4 * t4) =
            make_float4(aLx, aLy, aLz, aLw);
        *reinterpret_cast<float4*>(s_ldsf + (2 * cp + 1) * CSTRIDE_U + S2_OFF + 4 * t4) =
            make_float4(aHx, aHy, aHz, aHw);
    }
}

// ===== Kernel C: fused build + node; block = (pass, e, cg4); 1 node/lane =====
// Node body = verified single-node skeleton (R8/R11/R13/R15) with bf16 tri
// table (8-pad runs): each ds_read_b128 now feeds 8 coefficients. Do NOT widen
// to 2 nodes/lane (spilled: R9/R10/R12) or chain-split (spilled: R14). Bounds
// stay (256,4): (256,5) capped VGPR at 48 and spilled 3 GB (R9).
__global__ void __launch_bounds__(NTHREADS, 4) node_kernel(
    const float* __restrict__ x, const float* __restrict__ ws,
    const float* __restrict__ U1_0e, const float* __restrict__ U1_1o,
    const float* __restrict__ W1_0e, const float* __restrict__ W2_0e,
    const float* __restrict__ W3_0e,
    const float* __restrict__ W1_1o, const float* __restrict__ W2_1o,
    const float* __restrict__ W3_1o,
    float* __restrict__ out) {
    __shared__ __align__(16) unsigned s_ldsu[4 * CSTRIDE_U];   // 13.9 KiB
    __shared__ __align__(16) float s_w3[4 * P3_1];
    __shared__ __align__(16) float s_w2[4 * P2_1];
    __shared__ int s_nid[NB];
    float* s_ldsf = reinterpret_cast<float*>(s_ldsu);
    const int tid = threadIdx.x, bid = blockIdx.x;
    const int pass = bid / (NE * (NC / 4));
    const int rest = bid % (NE * (NC / 4));
    const int e = rest / (NC / 4);
    const int cg = (rest % (NC / 4)) * 4;

    const int P3c = pass == 0 ? P3_0 : P3_1;
    const int P2c = pass == 0 ? P2_0 : P2_1;
    const int k3b = pass == 0 ? 0 : P3_0 + (pass - 1) * P3_1;
    const int k2b = pass == 0 ? 0 : P2_0 + (pass - 1) * P2_1;
    const float* W3e = (pass == 0 ? W3_0e + (size_t)e * P3_0 * NC
                                  : W3_1o + (size_t)e * P3_1 * NC) + cg;
    const float* W2e = (pass == 0 ? W2_0e + (size_t)e * P2_0 * NC
                                  : W2_1o + (size_t)e * P2_1 * NC) + cg;
    const float* W1e = (pass == 0 ? W1_0e : W1_1o) + e * NC + cg;
    const float* U1p = pass == 0 ? U1_0e : U1_1o + (pass - 1) * NL;
    const float* sym3p = ws + OFF_SYM3A + (size_t)k3b * TRI_P8;
    const float* sym2p = ws + OFF_SYM2A + (size_t)k2b * DUO_P;

    const int* cnt = (const int*)ws + OFF_CNT;
    const int* nid = (const int*)ws + OFF_NID + e * NB;
    const int nn = cnt[e];
    for (int i = tid; i < nn; i += NTHREADS) s_nid[i] = nid[i];

    // stage W + S1
    if (tid < P3c) {
        *reinterpret_cast<float4*>(&s_w3[4 * tid]) =
            *reinterpret_cast<const float4*>(W3e + tid * NC);
    } else if (tid >= 64 && tid < 64 + P2c) {
        const int k = tid - 64;
        *reinterpret_cast<float4*>(&s_w2[4 * k]) =
            *reinterpret_cast<const float4*>(W2e + k * NC);
    } else if (tid >= 128 && tid < 192) {
        const int t = tid - 128;                 // ch = t>>4, i = t&15
        s_ldsf[(t >> 4) * CSTRIDE_U + S1_OFF + (t & 15)] = U1p[t & 15] * W1e[t >> 4];
    }
    __syncthreads();

    if (pass == 0) build_lds<P3_0, P2_0>(sym3p, sym2p, s_w3, s_w2, s_ldsu, tid);
    else           build_lds<P3_1, P2_1>(sym3p, sym2p, s_w3, s_w2, s_ldsu, tid);
    __syncthreads();

    const int w = tid >> 6;        // wave <-> channel
    const int lane = tid & 63;
    const int cc = cg + w;
    const unsigned* Tchu = s_ldsu + w * CSTRIDE_U;
    const float* Tchf = reinterpret_cast<const float*>(Tchu);
    const int col = pass == 0 ? cc : NC + 3 * cc + (pass - 1);

#pragma unroll 1
    for (int base = 0; base < nn; base += 64) {
        const int slot = base + lane;
        const bool val = slot < nn;
        const int b = s_nid[val ? slot : 0];
        const float* xp = x + ((size_t)b * NC + cc) * NL;
        float xr[NL];
#pragma unroll
        for (int v4 = 0; v4 < 4; ++v4)
            reinterpret_cast<float4*>(xr)[v4] = reinterpret_cast<const float4*>(xp)[v4];

        float acc = 0.f;
        int t3 = 0, t2 = 0;                      // t3 in u32 words
#pragma unroll
        for (int i = 0; i < 16; ++i) {
            float gi = Tchf[S1_OFF + i];
            const int L2 = 16 - i, PL2 = (L2 + 3) & ~3;
            float s2r[16];
#pragma unroll
            for (int q4 = 0; q4 < PL2 / 4; ++q4)
                reinterpret_cast<float4*>(s2r)[q4] =
                    *reinterpret_cast<const float4*>(Tchf + S2_OFF + t2 + 4 * q4);
            t2 += PL2;
#pragma unroll
            for (int jo = 0; jo < 16 - i; ++jo) {
                const int j = i + jo;
                float wv = s2r[jo];
                // chunk 0: 8 bf16 coefficients (one b128)
                {
                    const uint4 p0 = *reinterpret_cast<const uint4*>(Tchu + t3);
                    float f[8];
                    bfun8(p0, f);
#pragma unroll
                    for (int m8 = 0; m8 < 8; ++m8)
                        wv = fmaf(f[m8], xr[(j + m8) & 15], wv);
                }
                if (j < 8) {  // run length 16: second chunk
                    const uint4 p1 = *reinterpret_cast<const uint4*>(Tchu + t3 + 4);
                    float f[8];
                    bfun8(p1, f);
#pragma unroll
                    for (int m8 = 0; m8 < 8; ++m8)
                        wv = fmaf(f[m8], xr[(j + 8 + m8) & 15], wv);
                    t3 += 8;
                } else {
                    t3 += 4;
                }
                gi = fmaf(wv, xr[j], gi);
            }
            acc = fmaf(gi, xr[i], acc);
        }
        if (val) out[(size_t)b * NOUT + col] = acc;
    }
}

// ===================== fallback (ws too small): fp32 4-pad, gather from raw U =====================
template <int P3, int P2>
__device__ __forceinline__ void build_gather_f(const float* __restrict__ U3,
                                               const float* __restrict__ U2,
                                               const float* __restrict__ s_w3,
                                               const float* __restrict__ s_w2,
                                               float* __restrict__ lds, int tid) {
#pragma unroll 1
    for (int t = tid; t < TRI_P; t += NTHREADS) {
        int i, j, m; const bool v = tri_from_padded(t, i, j, m);
        float a0 = 0, a1 = 0, a2 = 0, a3 = 0;
        if (v) {
            int ng = 1, g1 = 0, g2 = 0, g3 = 0, g4 = 0, g5 = 0;
            const int g0 = ((i * 16 + j) * 16 + m);
            if (i == j && j == m) { ng = 1; }
            else if (i == j) { g1 = ((i * 16 + m) * 16 + i); g2 = ((m * 16 + i) * 16 + i); ng = 3; }
            else if (j == m) { g1 = ((j * 16 + i) * 16 + j); g2 = ((j * 16 + j) * 16 + i); ng = 3; }
            else { g1 = ((i * 16 + m) * 16 + j); g2 = ((j * 16 + i) * 16 + m);
                   g3 = ((j * 16 + m) * 16 + i); g4 = ((m * 16 + i) * 16 + j);
                   g5 = ((m * 16 + j) * 16 + i); ng = 6; }
#pragma unroll 1
            for (int k = 0; k < P3; ++k) {
                float u = U3[(size_t)g0 * P3 + k];
                if (ng > 1) u += U3[(size_t)g1 * P3 + k] + U3[(size_t)g2 * P3 + k];
                if (ng == 6) u += U3[(size_t)g3 * P3 + k] + U3[(size_t)g4 * P3 + k]
                                + U3[(size_t)g5 * P3 + k];
                const float4 wk = reinterpret_cast<const float4*>(s_w3)[k];
                a0 = fmaf(u, wk.x, a0); a1 = fmaf(u, wk.y, a1);
                a2 = fmaf(u, wk.z, a2); a3 = fmaf(u, wk.w, a3);
            }
        }
        lds[0 * CSTRIDE + t] = a0; lds[1 * CSTRIDE + t] = a1;
        lds[2 * CSTRIDE + t] = a2; lds[3 * CSTRIDE + t] = a3;
    }
    if (tid < DUO_P) {
        int i, j; const bool v = duo_from_padded(tid, i, j);
        float a0 = 0, a1 = 0, a2 = 0, a3 = 0;
        if (v) {
#pragma unroll 1
            for (int k = 0; k < P2; ++k) {
                float u = U2[(size_t)((i << 4) + j) * P2 + k];
                if (i < j) u += U2[(size_t)((j << 4) + i) * P2 + k];
                const float4 wk = reinterpret_cast<const float4*>(s_w2)[k];
                a0 = fmaf(u, wk.x, a0); a1 = fmaf(u, wk.y, a1);
                a2 = fmaf(u, wk.z, a2); a3 = fmaf(u, wk.w, a3);
            }
        }
        lds[0 * CSTRIDE + TRI_P + tid] = a0; lds[1 * CSTRIDE + TRI_P + tid] = a1;
        lds[2 * CSTRIDE + TRI_P + tid] = a2; lds[3 * CSTRIDE + TRI_P + tid] = a3;
    }
}

__global__ void __launch_bounds__(NTHREADS, 4) symcon_fallback(
    const float* __restrict__ x, const float* __restrict__ y,
    const float* __restrict__ U1_0e, const float* __restrict__ U2_0e,
    const float* __restrict__ U3_0e,
    const float* __restrict__ W1_0e, const float* __restrict__ W2_0e,
    const float* __restrict__ W3_0e,
    const float* __restrict__ U1_1o, const float* __restrict__ U2_1o,
    const float* __restrict__ U3_1o,
    const float* __restrict__ W1_1o, const float* __restrict__ W2_1o,
    const float* __restrict__ W3_1o,
    float* __restrict__ out)
{
    __shared__ __align__(16) float s_lds[4 * CSTRIDE];
    __shared__ __align__(16) float s_w3[4 * P3_1 + 4];
    __shared__ __align__(16) float s_w2[4 * P2_1];
    __shared__ int s_nid[NB];
    __shared__ int s_scan[NTHREADS];

    const int tid = threadIdx.x;
    const int bid = blockIdx.x;
    const int s   = bid & 1;
    const int e   = (bid >> 1) % NE;
    const int cg  = (bid / (2 * NE)) * 4;

    unsigned pat = 0;
#pragma unroll
    for (int q = 0; q < 4; ++q)
        if (y[(tid * 4 + q) * NE + e] > 0.5f) pat |= (1u << q);
    const int lc = __popc(pat);
    s_scan[tid] = lc;
    __syncthreads();
#pragma unroll
    for (int off = 1; off < NTHREADS; off <<= 1) {
        const int add = (tid >= off) ? s_scan[tid - off] : 0;
        __syncthreads();
        s_scan[tid] += add;
        __syncthreads();
    }
    const int nn = s_scan[NTHREADS - 1];
    {
        int pos = s_scan[tid] - lc;
#pragma unroll
        for (int q = 0; q < 4; ++q)
            if (pat & (1u << q)) s_nid[pos++] = tid * 4 + q;
    }
    __syncthreads();

    const int half = (nn + 1) >> 1;
    const int l0 = s * half, l1 = min(nn, l0 + half);
    const int L = l1 - l0;
    if (L <= 0) return;

    const int w    = tid >> 6;
    const int ch   = (tid >> 4) & 3;
    const int nsub = tid & 15;
    const int cc   = cg + ch;
    const int chunk = (L + 3) >> 2;
    const int wbase = l0 + w * chunk;
    const int wend  = min(l1, wbase + chunk);
    const int iters = (chunk + 15) >> 4;
    const float* Tch = s_lds + ch * CSTRIDE;

#pragma unroll 1
    for (int pass = 0; pass < 4; ++pass) {
        const float* U3r = pass == 0 ? U3_0e : U3_1o + (size_t)(pass - 1) * 4096 * P3_1;
        const float* U2r = pass == 0 ? U2_0e : U2_1o + (size_t)(pass - 1) * 256 * P2_1;
        const float* U1p = (pass == 0 ? U1_0e : U1_1o + (pass - 1) * NL);
        const float* W3e = (pass == 0 ? W3_0e + (size_t)e * P3_0 * NC
                                      : W3_1o + (size_t)e * P3_1 * NC) + cg;
        const float* W2e = (pass == 0 ? W2_0e + (size_t)e * P2_0 * NC
                                      : W2_1o + (size_t)e * P2_1 * NC) + cg;
        const float* W1e = (pass == 0 ? W1_0e : W1_1o) + e * NC + cg;
        const int P3c = pass == 0 ? P3_0 : P3_1;
        const int P2c = pass == 0 ? P2_0 : P2_1;
        const int col = pass == 0 ? cc : NC + 3 * cc + (pass - 1);

        if (tid < 4 * P3c) {
            s_w3[tid] = W3e[(tid >> 2) * NC + (tid & 3)];
        } else if (tid >= 152 && tid < 152 + 4 * P2c) {
            const int t = tid - 152;
            s_w2[t] = W2e[(t >> 2) * NC + (t & 3)];
        } else if (tid >= 192) {
            const int t = tid - 192;
            s_lds[(t >> 4) * CSTRIDE + 1200 + (t & 15)] = U1p[t & 15] * W1e[t >> 4];
        }
        __syncthreads();

        if (pass == 0) build_gather_f<P3_0, P2_0>(U3r, U2r, s_w3, s_w2, s_lds, tid);
        else           build_gather_f<P3_1, P2_1>(U3r, U2r, s_w3, s_w2, s_lds, tid);
        __syncthreads();

#pragma unroll 1
        for (int it = 0; it < iters; ++it) {
            const int slot = wbase + it * 16 + nsub;
            const bool val = slot < wend;
            const int b = s_nid[val ? slot : l0];
            const float* xp = x + ((size_t)b * NC + cc) * NL;
            float xr[NL];
#pragma unroll
            for (int v4 = 0; v4 < 4; ++v4)
                reinterpret_cast<float4*>(xr)[v4] = reinterpret_cast<const float4*>(xp)[v4];

            float acc = 0.f;
            int t3 = 0, t2 = 0;
#pragma unroll
            for (int i = 0; i < 16; ++i) {
                float gi = Tch[1200 + i];
                const int L2 = 16 - i, PL2 = (L2 + 3) & ~3;
                float s2r[16];
#pragma unroll
                for (int q4 = 0; q4 < PL2 / 4; ++q4)
                    reinterpret_cast<float4*>(s2r)[q4] =
                        *reinterpret_cast<const float4*>(Tch + TRI_P + t2 + 4 * q4);
                t2 += PL2;
#pragma unroll
                for (int jo = 0; jo < 16 - i; ++jo) {
                    const int j = i + jo;
                    float wv = s2r[jo];
                    const int Lr = 16 - j, PLr = (Lr + 3) & ~3;
#pragma unroll
                    for (int q4 = 0; q4 < PLr / 4; ++q4) {
                        const float4 tv = *reinterpret_cast<const float4*>(Tch + t3 + 4 * q4);
                        wv = fmaf(tv.x, xr[(j + 4 * q4 + 0) & 15], wv);
                        wv = fmaf(tv.y, xr[(j + 4 * q4 + 1) & 15], wv);
                        wv = fmaf(tv.z, xr[(j + 4 * q4 + 2) & 15], wv);
                        wv = fmaf(tv.w, xr[(j + 4 * q4 + 3) & 15], wv);
                    }
                    t3 += PLr;
                    gi = fmaf(wv, xr[j], gi);
                }
                acc = fmaf(gi, xr[i], acc);
            }
            if (val) out[(size_t)b * NOUT + col] = acc;
        }
        __syncthreads();
    }
}

extern "C" void kernel_launch(void* const* d_in, const int* in_sizes, int n_in,
                              void* d_out, int out_size, void* d_ws, size_t ws_size,
                              hipStream_t stream) {
    const float* x     = (const float*)d_in[0];
    const float* y     = (const float*)d_in[1];
    const float* U1_0e = (const float*)d_in[2];
    const float* U2_0e = (const float*)d_in[3];
    const float* U3_0e = (const float*)d_in[4];
    const float* W1_0e = (const float*)d_in[5];
    const float* W2_0e = (const float*)d_in[6];
    const float* W3_0e = (const float*)d_in[7];
    const float* U1_1o = (const float*)d_in[8];
    const float* U2_1o = (const float*)d_in[9];
    const float* U3_1o = (const float*)d_in[10];
    const float* W1_1o = (const float*)d_in[11];
    const float* W2_1o = (const float*)d_in[12];
    const float* W3_1o = (const float*)d_in[13];
    float* out = (float*)d_out;
    float* ws = (float*)d_ws;

    if (ws_size >= (size_t)WS_REQ * sizeof(float)) {
        const int symBlocks = (SYM_TOTAL + NTHREADS - 1) / NTHREADS;
        hipLaunchKernelGGL(prep_kernel, dim3(NE + symBlocks), dim3(NTHREADS), 0, stream,
                           y, U3_0e, U3_1o, U2_0e, U2_1o, ws);
        hipLaunchKernelGGL(node_kernel, dim3(4 * NE * (NC / 4)), dim3(NTHREADS), 0, stream,
                           x, ws, U1_0e, U1_1o, W1_0e, W2_0e, W3_0e,
                           W1_1o, W2_1o, W3_1o, out);
    } else {
        hipLaunchKernelGGL(symcon_fallback, dim3(NE * (NC / 4) * NSPLIT), dim3(NTHREADS), 0, stream,
                           x, y, U1_0e, U2_0e, U3_0e, W1_0e, W2_0e, W3_0e,
                           U1_1o, U2_1o, U3_1o, W1_1o, W2_1o, W3_1o, out);
    }
}

// Round 17
// 89.085 us; speedup vs baseline: 2.6836x; 2.6836x over previous
//
#include <hip/hip_runtime.h>

namespace {
constexpr int NB = 1024, NC = 128, NL = 16, NE = 10, NOUT = 4 * NC;
constexpr int NTHREADS = 256;
constexpr int NSPLIT = 2;
constexpr int P3_0 = 23, P2_0 = 4, P3_1 = 37, P2_1 = 6;
constexpr int TRI_P = 1040, DUO_P = 160, CSTRIDE = 1224;
constexpr int U3ROWS = P3_0 + 3 * P3_1;          // 134
constexpr int U2ROWS = P2_0 + 3 * P2_1;          // 22
constexpr int SYM3_FLOATS = U3ROWS * TRI_P;      // 139360
constexpr int SYM2_FLOATS = U2ROWS * DUO_P;      // 3520
constexpr int SYM_TOTAL = SYM3_FLOATS + SYM2_FLOATS;  // 142880
// ws layout (float offsets)
constexpr int OFF_CNT = 0;                        // 16 ints
constexpr int OFF_NID = 16;                       // NE*NB ints -> end 10256
constexpr int OFF_SYM3A = 10272;
constexpr int OFF_SYM2A = OFF_SYM3A + SYM3_FLOATS;   // 149632
constexpr int WS_REQ = OFF_SYM2A + SYM2_FLOATS;      // 153152 floats (~613 KB)
}

__device__ __forceinline__ bool tri_from_padded(int t, int& ri, int& rj, int& rm) {
    int pos = 0;
    for (int i = 0; i < 16; ++i)
        for (int j = i; j < 16; ++j) {
            const int L = 16 - j, PL = (L + 3) & ~3;
            if (t < pos + PL) { ri = i; rj = j; rm = j + (t - pos); return (t - pos) < L; }
            pos += PL;
        }
    return false;
}
__device__ __forceinline__ bool duo_from_padded(int t, int& ri, int& rj) {
    int pos = 0;
    for (int i = 0; i < 16; ++i) {
        const int L = 16 - i, PL = (L + 3) & ~3;
        if (t < pos + PL) { ri = i; rj = i + (t - pos); return (t - pos) < L; }
        pos += PL;
    }
    return false;
}

// symmetrized U tables, run-padded, k-major; pad positions write 0.
__device__ __forceinline__ void sym_body(int n,
    const float* __restrict__ U3_0e, const float* __restrict__ U3_1o,
    const float* __restrict__ U2_0e, const float* __restrict__ U2_1o,
    float* __restrict__ dst) {
    if (n < SYM3_FLOATS) {
        const int kk = n / TRI_P, t = n - kk * TRI_P;
        int pass, k, P; const float* U;
        if (kk < P3_0) { pass = 0; k = kk; P = P3_0; U = U3_0e; }
        else { const int r = kk - P3_0; pass = 1 + r / P3_1; k = r - (pass - 1) * P3_1;
               P = P3_1; U = U3_1o + (size_t)(pass - 1) * 4096 * P3_1; }
        int i, j, m; float s = 0.f;
        if (tri_from_padded(t, i, j, m)) {
            auto u3 = [&](int a, int b, int c) {
                return U[(size_t)(((a << 4) + b) * 16 + c) * P + k]; };
            s = u3(i, j, m);
            if (i == j && j == m) {}
            else if (i == j) s += u3(i, m, i) + u3(m, i, i);
            else if (j == m) s += u3(j, i, j) + u3(j, j, i);
            else s += u3(i, m, j) + u3(j, i, m) + u3(j, m, i) + u3(m, i, j) + u3(m, j, i);
        }
        dst[n] = s;
    } else if (n < SYM_TOTAL) {
        const int r = n - SYM3_FLOATS;
        const int kk = r / DUO_P, t = r - kk * DUO_P;
        int pass, k, P; const float* U;
        if (kk < P2_0) { pass = 0; k = kk; P = P2_0; U = U2_0e; }
        else { const int q = kk - P2_0; pass = 1 + q / P2_1; k = q - (pass - 1) * P2_1;
               P = P2_1; U = U2_1o + (size_t)(pass - 1) * 256 * P2_1; }
        int i, j; float s = 0.f;
        if (duo_from_padded(t, i, j)) {
            auto u2 = [&](int a, int b) { return U[(size_t)((a << 4) + b) * P + k]; };
            s = u2(i, j) + (i < j ? u2(j, i) : 0.f);
        }
        dst[n] = s;
    }
}

// ===== Kernel A: blocks 0..NE-1 gather node lists; rest build sym tables =====
__global__ void prep_kernel(const float* __restrict__ y,
                            const float* __restrict__ U3_0e, const float* __restrict__ U3_1o,
                            const float* __restrict__ U2_0e, const float* __restrict__ U2_1o,
                            float* __restrict__ ws) {
    const int bid = blockIdx.x, tid = threadIdx.x;
    if (bid < NE) {
        __shared__ int s_scan[NTHREADS];
        const int e = bid;
        unsigned pat = 0;
#pragma unroll
        for (int q = 0; q < 4; ++q)
            if (y[(tid * 4 + q) * NE + e] > 0.5f) pat |= (1u << q);
        const int lc = __popc(pat);
        s_scan[tid] = lc;
        __syncthreads();
#pragma unroll
        for (int off = 1; off < NTHREADS; off <<= 1) {
            const int add = (tid >= off) ? s_scan[tid - off] : 0;
            __syncthreads();
            s_scan[tid] += add;
            __syncthreads();
        }
        int* cnt = (int*)ws + OFF_CNT;
        int* nid = (int*)ws + OFF_NID + e * NB;
        int pos = s_scan[tid] - lc;
#pragma unroll
        for (int q = 0; q < 4; ++q)
            if (pat & (1u << q)) nid[pos++] = tid * 4 + q;
        if (tid == 0) cnt[e] = s_scan[NTHREADS - 1];
    } else {
        const int n = (bid - NE) * NTHREADS + tid;
        sym_body(n, U3_0e, U3_1o, U2_0e, U2_1o, ws + OFF_SYM3A);
    }
}

// ===== build UW tile in LDS: item = (t4, channel-pair) =====
// 2x redundant sym reads (vs 4x in R13's (t4,ch)), only 8 accumulators + 1
// float4 + 2 scalars live (~20 regs) — fits the 64-VGPR envelope this kernel
// family must respect (R14's 16-acc version spilled: 2.8 GB scratch traffic).
template <int P3c, int P2c>
__device__ __forceinline__ void build_lds(const float* __restrict__ sym3p,
                                          const float* __restrict__ sym2p,
                                          const float* __restrict__ s_w3,
                                          const float* __restrict__ s_w2,
                                          float* __restrict__ s_lds, int tid)
{
#pragma unroll 1
    for (int idx = tid; idx < (TRI_P / 4) * 2; idx += NTHREADS) {
        const int t4 = idx >> 1, cp = idx & 1;       // channels 2cp, 2cp+1
        float aLx = 0, aLy = 0, aLz = 0, aLw = 0;
        float aHx = 0, aHy = 0, aHz = 0, aHw = 0;
#pragma unroll 4
        for (int k = 0; k < P3c; ++k) {
            const float4 u = *reinterpret_cast<const float4*>(sym3p + (size_t)k * TRI_P + 4 * t4);
            const float wL = s_w3[4 * k + 2 * cp];
            const float wH = s_w3[4 * k + 2 * cp + 1];
            aLx = fmaf(u.x, wL, aLx); aLy = fmaf(u.y, wL, aLy);
            aLz = fmaf(u.z, wL, aLz); aLw = fmaf(u.w, wL, aLw);
            aHx = fmaf(u.x, wH, aHx); aHy = fmaf(u.y, wH, aHy);
            aHz = fmaf(u.z, wH, aHz); aHw = fmaf(u.w, wH, aHw);
        }
        *reinterpret_cast<float4*>(s_lds + (2 * cp) * CSTRIDE + 4 * t4) =
            make_float4(aLx, aLy, aLz, aLw);
        *reinterpret_cast<float4*>(s_lds + (2 * cp + 1) * CSTRIDE + 4 * t4) =
            make_float4(aHx, aHy, aHz, aHw);
    }
    if (tid < (DUO_P / 4) * 2) {
        const int t4 = tid >> 1, cp = tid & 1;
        float aLx = 0, aLy = 0, aLz = 0, aLw = 0;
        float aHx = 0, aHy = 0, aHz = 0, aHw = 0;
#pragma unroll
        for (int k = 0; k < P2c; ++k) {
            const float4 u = *reinterpret_cast<const float4*>(sym2p + (size_t)k * DUO_P + 4 * t4);
            const float wL = s_w2[4 * k + 2 * cp];
            const float wH = s_w2[4 * k + 2 * cp + 1];
            aLx = fmaf(u.x, wL, aLx); aLy = fmaf(u.y, wL, aLy);
            aLz = fmaf(u.z, wL, aLz); aLw = fmaf(u.w, wL, aLw);
            aHx = fmaf(u.x, wH, aHx); aHy = fmaf(u.y, wH, aHy);
            aHz = fmaf(u.z, wH, aHz); aHw = fmaf(u.w, wH, aHw);
        }
        *reinterpret_cast<float4*>(s_lds + (2 * cp) * CSTRIDE + TRI_P + 4 * t4) =
            make_float4(aLx, aLy, aLz, aLw);
        *reinterpret_cast<float4*>(s_lds + (2 * cp + 1) * CSTRIDE + TRI_P + 4 * t4) =
            make_float4(aHx, aHy, aHz, aHw);
    }
}

// ===== Kernel C: fused build + node; block = (pass, e, cg4); 1 node/lane =====
// Node body = R8/R11/R13/R15-verified single-node form, UNCHANGED. The ~64-VGPR
// envelope is a hard wall (5 spill failures: R9/R10/R12/R14/R16) — do not widen
// nodes/lane, chain-split, or pack bf16. Bounds stay (256,4).
__global__ void __launch_bounds__(NTHREADS, 4) node_kernel(
    const float* __restrict__ x, const float* __restrict__ ws,
    const float* __restrict__ U1_0e, const float* __restrict__ U1_1o,
    const float* __restrict__ W1_0e, const float* __restrict__ W2_0e,
    const float* __restrict__ W3_0e,
    const float* __restrict__ W1_1o, const float* __restrict__ W2_1o,
    const float* __restrict__ W3_1o,
    float* __restrict__ out) {
    __shared__ __align__(16) float s_lds[4 * CSTRIDE];   // 19.6 KiB
    __shared__ __align__(16) float s_w3[4 * P3_1];
    __shared__ __align__(16) float s_w2[4 * P2_1];
    __shared__ int s_nid[NB];
    const int tid = threadIdx.x, bid = blockIdx.x;
    const int pass = bid / (NE * (NC / 4));
    const int rest = bid % (NE * (NC / 4));
    const int e = rest / (NC / 4);
    const int cg = (rest % (NC / 4)) * 4;

    const int P3c = pass == 0 ? P3_0 : P3_1;
    const int P2c = pass == 0 ? P2_0 : P2_1;
    const int k3b = pass == 0 ? 0 : P3_0 + (pass - 1) * P3_1;
    const int k2b = pass == 0 ? 0 : P2_0 + (pass - 1) * P2_1;
    const float* W3e = (pass == 0 ? W3_0e + (size_t)e * P3_0 * NC
                                  : W3_1o + (size_t)e * P3_1 * NC) + cg;
    const float* W2e = (pass == 0 ? W2_0e + (size_t)e * P2_0 * NC
                                  : W2_1o + (size_t)e * P2_1 * NC) + cg;
    const float* W1e = (pass == 0 ? W1_0e : W1_1o) + e * NC + cg;
    const float* U1p = pass == 0 ? U1_0e : U1_1o + (pass - 1) * NL;
    const float* sym3p = ws + OFF_SYM3A + (size_t)k3b * TRI_P;
    const float* sym2p = ws + OFF_SYM2A + (size_t)k2b * DUO_P;

    const int* cnt = (const int*)ws + OFF_CNT;
    const int* nid = (const int*)ws + OFF_NID + e * NB;
    const int nn = cnt[e];
    for (int i = tid; i < nn; i += NTHREADS) s_nid[i] = nid[i];

    // stage W + S1
    if (tid < P3c) {
        *reinterpret_cast<float4*>(&s_w3[4 * tid]) =
            *reinterpret_cast<const float4*>(W3e + tid * NC);
    } else if (tid >= 64 && tid < 64 + P2c) {
        const int k = tid - 64;
        *reinterpret_cast<float4*>(&s_w2[4 * k]) =
            *reinterpret_cast<const float4*>(W2e + k * NC);
    } else if (tid >= 128 && tid < 192) {
        const int t = tid - 128;                 // ch = t>>4, i = t&15
        s_lds[(t >> 4) * CSTRIDE + 1200 + (t & 15)] = U1p[t & 15] * W1e[t >> 4];
    }
    __syncthreads();

    // build UW tile in LDS from pre-symmetrized tables (chpair items)
    if (pass == 0) build_lds<P3_0, P2_0>(sym3p, sym2p, s_w3, s_w2, s_lds, tid);
    else           build_lds<P3_1, P2_1>(sym3p, sym2p, s_w3, s_w2, s_lds, tid);
    __syncthreads();

    const int w = tid >> 6;        // wave <-> channel
    const int lane = tid & 63;
    const int cc = cg + w;
    const float* Tch = s_lds + w * CSTRIDE;
    const int col = pass == 0 ? cc : NC + 3 * cc + (pass - 1);

#pragma unroll 1
    for (int base = 0; base < nn; base += 64) {
        const int slot = base + lane;
        const bool val = slot < nn;
        const int b = s_nid[val ? slot : 0];
        const float* xp = x + ((size_t)b * NC + cc) * NL;
        float xr[NL];
#pragma unroll
        for (int v4 = 0; v4 < 4; ++v4)
            reinterpret_cast<float4*>(xr)[v4] = reinterpret_cast<const float4*>(xp)[v4];

        float acc = 0.f;
        int t3 = 0, t2 = 0;
#pragma unroll
        for (int i = 0; i < 16; ++i) {
            float gi = Tch[1200 + i];
            const int L2 = 16 - i, PL2 = (L2 + 3) & ~3;
            float s2r[16];
#pragma unroll
            for (int q4 = 0; q4 < PL2 / 4; ++q4)
                reinterpret_cast<float4*>(s2r)[q4] =
                    *reinterpret_cast<const float4*>(Tch + TRI_P + t2 + 4 * q4);
            t2 += PL2;
#pragma unroll
            for (int jo = 0; jo < 16 - i; ++jo) {
                const int j = i + jo;
                float wv = s2r[jo];
                const int Lr = 16 - j, PLr = (Lr + 3) & ~3;
#pragma unroll
                for (int q4 = 0; q4 < PLr / 4; ++q4) {
                    const float4 tv = *reinterpret_cast<const float4*>(Tch + t3 + 4 * q4);
                    wv = fmaf(tv.x, xr[(j + 4 * q4 + 0) & 15], wv);
                    wv = fmaf(tv.y, xr[(j + 4 * q4 + 1) & 15], wv);
                    wv = fmaf(tv.z, xr[(j + 4 * q4 + 2) & 15], wv);
                    wv = fmaf(tv.w, xr[(j + 4 * q4 + 3) & 15], wv);
                }
                t3 += PLr;
                gi = fmaf(wv, xr[j], gi);
            }
            acc = fmaf(gi, xr[i], acc);
        }
        if (val) out[(size_t)b * NOUT + col] = acc;
    }
}

// ===================== fallback (ws too small): gather from raw U =====================
template <int P3, int P2>
__device__ __forceinline__ void build_gather_f(const float* __restrict__ U3,
                                               const float* __restrict__ U2,
                                               const float* __restrict__ s_w3,
                                               const float* __restrict__ s_w2,
                                               float* __restrict__ lds, int tid) {
#pragma unroll 1
    for (int t = tid; t < TRI_P; t += NTHREADS) {
        int i, j, m; const bool v = tri_from_padded(t, i, j, m);
        float a0 = 0, a1 = 0, a2 = 0, a3 = 0;
        if (v) {
            int ng = 1, g1 = 0, g2 = 0, g3 = 0, g4 = 0, g5 = 0;
            const int g0 = ((i * 16 + j) * 16 + m);
            if (i == j && j == m) { ng = 1; }
            else if (i == j) { g1 = ((i * 16 + m) * 16 + i); g2 = ((m * 16 + i) * 16 + i); ng = 3; }
            else if (j == m) { g1 = ((j * 16 + i) * 16 + j); g2 = ((j * 16 + j) * 16 + i); ng = 3; }
            else { g1 = ((i * 16 + m) * 16 + j); g2 = ((j * 16 + i) * 16 + m);
                   g3 = ((j * 16 + m) * 16 + i); g4 = ((m * 16 + i) * 16 + j);
                   g5 = ((m * 16 + j) * 16 + i); ng = 6; }
#pragma unroll 1
            for (int k = 0; k < P3; ++k) {
                float u = U3[(size_t)g0 * P3 + k];
                if (ng > 1) u += U3[(size_t)g1 * P3 + k] + U3[(size_t)g2 * P3 + k];
                if (ng == 6) u += U3[(size_t)g3 * P3 + k] + U3[(size_t)g4 * P3 + k]
                                + U3[(size_t)g5 * P3 + k];
                const float4 wk = reinterpret_cast<const float4*>(s_w3)[k];
                a0 = fmaf(u, wk.x, a0); a1 = fmaf(u, wk.y, a1);
                a2 = fmaf(u, wk.z, a2); a3 = fmaf(u, wk.w, a3);
            }
        }
        lds[0 * CSTRIDE + t] = a0; lds[1 * CSTRIDE + t] = a1;
        lds[2 * CSTRIDE + t] = a2; lds[3 * CSTRIDE + t] = a3;
    }
    if (tid < DUO_P) {
        int i, j; const bool v = duo_from_padded(tid, i, j);
        float a0 = 0, a1 = 0, a2 = 0, a3 = 0;
        if (v) {
#pragma unroll 1
            for (int k = 0; k < P2; ++k) {
                float u = U2[(size_t)((i << 4) + j) * P2 + k];
                if (i < j) u += U2[(size_t)((j << 4) + i) * P2 + k];
                const float4 wk = reinterpret_cast<const float4*>(s_w2)[k];
                a0 = fmaf(u, wk.x, a0); a1 = fmaf(u, wk.y, a1);
                a2 = fmaf(u, wk.z, a2); a3 = fmaf(u, wk.w, a3);
            }
        }
        lds[0 * CSTRIDE + TRI_P + tid] = a0; lds[1 * CSTRIDE + TRI_P + tid] = a1;
        lds[2 * CSTRIDE + TRI_P + tid] = a2; lds[3 * CSTRIDE + TRI_P + tid] = a3;
    }
}

__global__ void __launch_bounds__(NTHREADS, 4) symcon_fallback(
    const float* __restrict__ x, const float* __restrict__ y,
    const float* __restrict__ U1_0e, const float* __restrict__ U2_0e,
    const float* __restrict__ U3_0e,
    const float* __restrict__ W1_0e, const float* __restrict__ W2_0e,
    const float* __restrict__ W3_0e,
    const float* __restrict__ U1_1o, const float* __restrict__ U2_1o,
    const float* __restrict__ U3_1o,
    const float* __restrict__ W1_1o, const float* __restrict__ W2_1o,
    const float* __restrict__ W3_1o,
    float* __restrict__ out)
{
    __shared__ __align__(16) float s_lds[4 * CSTRIDE];
    __shared__ __align__(16) float s_w3[4 * P3_1 + 4];
    __shared__ __align__(16) float s_w2[4 * P2_1];
    __shared__ int s_nid[NB];
    __shared__ int s_scan[NTHREADS];

    const int tid = threadIdx.x;
    const int bid = blockIdx.x;
    const int s   = bid & 1;
    const int e   = (bid >> 1) % NE;
    const int cg  = (bid / (2 * NE)) * 4;

    unsigned pat = 0;
#pragma unroll
    for (int q = 0; q < 4; ++q)
        if (y[(tid * 4 + q) * NE + e] > 0.5f) pat |= (1u << q);
    const int lc = __popc(pat);
    s_scan[tid] = lc;
    __syncthreads();
#pragma unroll
    for (int off = 1; off < NTHREADS; off <<= 1) {
        const int add = (tid >= off) ? s_scan[tid - off] : 0;
        __syncthreads();
        s_scan[tid] += add;
        __syncthreads();
    }
    const int nn = s_scan[NTHREADS - 1];
    {
        int pos = s_scan[tid] - lc;
#pragma unroll
        for (int q = 0; q < 4; ++q)
            if (pat & (1u << q)) s_nid[pos++] = tid * 4 + q;
    }
    __syncthreads();

    const int half = (nn + 1) >> 1;
    const int l0 = s * half, l1 = min(nn, l0 + half);
    const int L = l1 - l0;
    if (L <= 0) return;

    const int w    = tid >> 6;
    const int ch   = (tid >> 4) & 3;
    const int nsub = tid & 15;
    const int cc   = cg + ch;
    const int chunk = (L + 3) >> 2;
    const int wbase = l0 + w * chunk;
    const int wend  = min(l1, wbase + chunk);
    const int iters = (chunk + 15) >> 4;
    const float* Tch = s_lds + ch * CSTRIDE;

#pragma unroll 1
    for (int pass = 0; pass < 4; ++pass) {
        const float* U3r = pass == 0 ? U3_0e : U3_1o + (size_t)(pass - 1) * 4096 * P3_1;
        const float* U2r = pass == 0 ? U2_0e : U2_1o + (size_t)(pass - 1) * 256 * P2_1;
        const float* U1p = (pass == 0 ? U1_0e : U1_1o + (pass - 1) * NL);
        const float* W3e = (pass == 0 ? W3_0e + (size_t)e * P3_0 * NC
                                      : W3_1o + (size_t)e * P3_1 * NC) + cg;
        const float* W2e = (pass == 0 ? W2_0e + (size_t)e * P2_0 * NC
                                      : W2_1o + (size_t)e * P2_1 * NC) + cg;
        const float* W1e = (pass == 0 ? W1_0e : W1_1o) + e * NC + cg;
        const int P3c = pass == 0 ? P3_0 : P3_1;
        const int P2c = pass == 0 ? P2_0 : P2_1;
        const int col = pass == 0 ? cc : NC + 3 * cc + (pass - 1);

        if (tid < 4 * P3c) {
            s_w3[tid] = W3e[(tid >> 2) * NC + (tid & 3)];
        } else if (tid >= 152 && tid < 152 + 4 * P2c) {
            const int t = tid - 152;
            s_w2[t] = W2e[(t >> 2) * NC + (t & 3)];
        } else if (tid >= 192) {
            const int t = tid - 192;
            s_lds[(t >> 4) * CSTRIDE + 1200 + (t & 15)] = U1p[t & 15] * W1e[t >> 4];
        }
        __syncthreads();

        if (pass == 0) build_gather_f<P3_0, P2_0>(U3r, U2r, s_w3, s_w2, s_lds, tid);
        else           build_gather_f<P3_1, P2_1>(U3r, U2r, s_w3, s_w2, s_lds, tid);
        __syncthreads();

#pragma unroll 1
        for (int it = 0; it < iters; ++it) {
            const int slot = wbase + it * 16 + nsub;
            const bool val = slot < wend;
            const int b = s_nid[val ? slot : l0];
            const float* xp = x + ((size_t)b * NC + cc) * NL;
            float xr[NL];
#pragma unroll
            for (int v4 = 0; v4 < 4; ++v4)
                reinterpret_cast<float4*>(xr)[v4] = reinterpret_cast<const float4*>(xp)[v4];

            float acc = 0.f;
            int t3 = 0, t2 = 0;
#pragma unroll
            for (int i = 0; i < 16; ++i) {
                float gi = Tch[1200 + i];
                const int L2 = 16 - i, PL2 = (L2 + 3) & ~3;
                float s2r[16];
#pragma unroll
                for (int q4 = 0; q4 < PL2 / 4; ++q4)
                    reinterpret_cast<float4*>(s2r)[q4] =
                        *reinterpret_cast<const float4*>(Tch + TRI_P + t2 + 4 * q4);
                t2 += PL2;
#pragma unroll
                for (int jo = 0; jo < 16 - i; ++jo) {
                    const int j = i + jo;
                    float wv = s2r[jo];
                    const int Lr = 16 - j, PLr = (Lr + 3) & ~3;
#pragma unroll
                    for (int q4 = 0; q4 < PLr / 4; ++q4) {
                        const float4 tv = *reinterpret_cast<const float4*>(Tch + t3 + 4 * q4);
                        wv = fmaf(tv.x, xr[(j + 4 * q4 + 0) & 15], wv);
                        wv = fmaf(tv.y, xr[(j + 4 * q4 + 1) & 15], wv);
                        wv = fmaf(tv.z, xr[(j + 4 * q4 + 2) & 15], wv);
                        wv = fmaf(tv.w, xr[(j + 4 * q4 + 3) & 15], wv);
                    }
                    t3 += PLr;
                    gi = fmaf(wv, xr[j], gi);
                }
                acc = fmaf(gi, xr[i], acc);
            }
            if (val) out[(size_t)b * NOUT + col] = acc;
        }
        __syncthreads();
    }
}

extern "C" void kernel_launch(void* const* d_in, const int* in_sizes, int n_in,
                              void* d_out, int out_size, void* d_ws, size_t ws_size,
                              hipStream_t stream) {
    const float* x     = (const float*)d_in[0];
    const float* y     = (const float*)d_in[1];
    const float* U1_0e = (const float*)d_in[2];
    const float* U2_0e = (const float*)d_in[3];
    const float* U3_0e = (const float*)d_in[4];
    const float* W1_0e = (const float*)d_in[5];
    const float* W2_0e = (const float*)d_in[6];
    const float* W3_0e = (const float*)d_in[7];
    const float* U1_1o = (const float*)d_in[8];
    const float* U2_1o = (const float*)d_in[9];
    const float* U3_1o = (const float*)d_in[10];
    const float* W1_1o = (const float*)d_in[11];
    const float* W2_1o = (const float*)d_in[12];
    const float* W3_1o = (const float*)d_in[13];
    float* out = (float*)d_out;
    float* ws = (float*)d_ws;

    if (ws_size >= (size_t)WS_REQ * sizeof(float)) {
        const int symBlocks = (SYM_TOTAL + NTHREADS - 1) / NTHREADS;
        hipLaunchKernelGGL(prep_kernel, dim3(NE + symBlocks), dim3(NTHREADS), 0, stream,
                           y, U3_0e, U3_1o, U2_0e, U2_1o, ws);
        hipLaunchKernelGGL(node_kernel, dim3(4 * NE * (NC / 4)), dim3(NTHREADS), 0, stream,
                           x, ws, U1_0e, U1_1o, W1_0e, W2_0e, W3_0e,
                           W1_1o, W2_1o, W3_1o, out);
    } else {
        hipLaunchKernelGGL(symcon_fallback, dim3(NE * (NC / 4) * NSPLIT), dim3(NTHREADS), 0, stream,
                           x, y, U1_0e, U2_0e, U3_0e, W1_0e, W2_0e, W3_0e,
                           U1_1o, U2_1o, U3_1o, W1_1o, W2_1o, W3_1o, out);
    }
}